// Round 1
// baseline (18397.437 us; speedup 1.0000x reference)
//
#include <hip/hip_runtime.h>
#include <math.h>

#define BB 8
#define SMEMN 128
#define DD 512
#define HH 8
#define HDIM 64
#define DFFN 2048
#define NLAYER 3
#define VV 128
#define LLEN 32
#define SOS_T 1
#define EOS_T 2
#define PAD_T 0

// ---------------------------------------------------------------- init tokens
__global__ __launch_bounds__(512) void init_tokens_kernel(int* __restrict__ tokens) {
    int i = threadIdx.x;
    if (i < BB * (LLEN + 1)) tokens[i] = (i % (LLEN + 1) == 0) ? SOS_T : PAD_T;
}

// ------------------------------------------------- memory @ ca_kv_w (hoisted)
// C[l] = memory[1024,512] @ Wkv[l][512,1024] + bkv[l]; split into Kmem/Vmem.
__global__ __launch_bounds__(256) void memkv_kernel(
    const float* __restrict__ mem, const float* __restrict__ Wkv, const float* __restrict__ bkv,
    float* __restrict__ Kmem, float* __restrict__ Vmem)
{
    int l = blockIdx.z;
    const float* Wl = Wkv + (size_t)l * DD * (2 * DD);
    const float* bl = bkv + l * (2 * DD);
    int brow = blockIdx.y * 64, bcol = blockIdx.x * 64;
    __shared__ float As[64][20];
    __shared__ float Bs[16][68];
    int tid = threadIdx.x;
    int ty = tid / 16, tx = tid % 16;
    float acc[4][4] = {};
    for (int k0 = 0; k0 < DD; k0 += 16) {
        {
            int r = tid >> 2, kk = (tid & 3) * 4;
            const float4 av = *(const float4*)(mem + (size_t)(brow + r) * DD + k0 + kk);
            As[r][kk] = av.x; As[r][kk + 1] = av.y; As[r][kk + 2] = av.z; As[r][kk + 3] = av.w;
        }
        {
            int kb = tid >> 4, j = (tid & 15) * 4;
            const float4 bv = *(const float4*)(Wl + (size_t)(k0 + kb) * (2 * DD) + bcol + j);
            Bs[kb][j] = bv.x; Bs[kb][j + 1] = bv.y; Bs[kb][j + 2] = bv.z; Bs[kb][j + 3] = bv.w;
        }
        __syncthreads();
        #pragma unroll
        for (int kk2 = 0; kk2 < 16; kk2++) {
            float a0 = As[ty * 4 + 0][kk2], a1 = As[ty * 4 + 1][kk2];
            float a2 = As[ty * 4 + 2][kk2], a3 = As[ty * 4 + 3][kk2];
            float b0 = Bs[kk2][tx * 4 + 0], b1 = Bs[kk2][tx * 4 + 1];
            float b2 = Bs[kk2][tx * 4 + 2], b3 = Bs[kk2][tx * 4 + 3];
            acc[0][0] += a0 * b0; acc[0][1] += a0 * b1; acc[0][2] += a0 * b2; acc[0][3] += a0 * b3;
            acc[1][0] += a1 * b0; acc[1][1] += a1 * b1; acc[1][2] += a1 * b2; acc[1][3] += a1 * b3;
            acc[2][0] += a2 * b0; acc[2][1] += a2 * b1; acc[2][2] += a2 * b2; acc[2][3] += a2 * b3;
            acc[3][0] += a3 * b0; acc[3][1] += a3 * b1; acc[3][2] += a3 * b2; acc[3][3] += a3 * b3;
        }
        __syncthreads();
    }
    for (int i = 0; i < 4; i++)
        for (int j = 0; j < 4; j++) {
            int row = brow + ty * 4 + i, colg = bcol + tx * 4 + j;
            float v = acc[i][j] + bl[colg];
            if (colg < DD) Kmem[((size_t)l * (BB * SMEMN) + row) * DD + colg] = v;
            else           Vmem[((size_t)l * (BB * SMEMN) + row) * DD + (colg - DD)] = v;
        }
}

// -------------------------------------------------------------------- embed
__global__ __launch_bounds__(256) void embed_kernel(
    const int* __restrict__ tokens, const float* __restrict__ emb,
    float* __restrict__ x, int t)
{
    int b = blockIdx.x, tid = threadIdx.x;
    int tok = tokens[b * (LLEN + 1) + t];
    int pos = (t == 0) ? 0 : (t + 1);
    const float neg_log1e4_over_d = -9.210340371976184f / 512.0f;
    for (int d = tid; d < DD; d += 256) {
        float freq = expf((float)(d & ~1) * neg_log1e4_over_d);
        float ang = (float)pos * freq;
        float pev = (d & 1) ? cosf(ang) : sinf(ang);
        x[b * DD + d] = emb[(size_t)tok * DD + d] * 22.62741699796952f + pev;
    }
}

// --------------------------------------------------------------- fused GEMV
// out[8,N] = LN?(in[8,K]) @ W[K,N] + bias (+relu) (+ LN?(res[8,512]) residual)
// Optionally routes cols [512,1024)->kcache, [1024,1536)->vcache (qkv stage).
template <int K_>
__global__ __launch_bounds__(256) void gemv_ln_kernel(
    const float* __restrict__ in,
    const float* __restrict__ in_g, const float* __restrict__ in_b,
    const float* __restrict__ W, const float* __restrict__ bias, int N,
    const float* __restrict__ res,
    const float* __restrict__ res_g, const float* __restrict__ res_b,
    float* __restrict__ out, int relu,
    float* __restrict__ kc, float* __restrict__ vc)
{
    const int KSL = 4, CPB = 64, KCH = 512, KPC = 128;
    __shared__ float xs[BB * KCH];
    __shared__ float rs[BB * DD];
    __shared__ float part[256 * BB];
    __shared__ float sm[BB], sr[BB], rm[BB], rr[BB];
    int tid = threadIdx.x;

    if (res) {
        for (int i = tid; i < BB * DD; i += 256) rs[i] = res[i];
        __syncthreads();
        if (res_g) {
            int r = tid >> 5, lane = tid & 31;
            float s = 0.f, q = 0.f;
            for (int k = lane; k < DD; k += 32) { float v = rs[r * DD + k]; s += v; q += v * v; }
            for (int off = 16; off; off >>= 1) { s += __shfl_down(s, off, 32); q += __shfl_down(q, off, 32); }
            if (lane == 0) { float m = s / DD; rm[r] = m; rr[r] = rsqrtf(q / DD - m * m + 1e-5f); }
            __syncthreads();
            for (int i = tid; i < BB * DD; i += 256) {
                int r2 = i >> 9, k = i & (DD - 1);
                rs[i] = (rs[i] - rm[r2]) * rr[r2] * res_g[k] + res_b[k];
            }
        }
    }

    int ks = tid / CPB, c = tid % CPB;
    int col = blockIdx.x * CPB + c;
    float acc[BB];
    #pragma unroll
    for (int r = 0; r < BB; r++) acc[r] = 0.f;

    for (int kc0 = 0; kc0 < K_; kc0 += KCH) {
        __syncthreads();
        for (int i = tid; i < BB * KCH; i += 256) {
            int r = i >> 9, k = i & (KCH - 1);
            xs[i] = in[(size_t)r * K_ + kc0 + k];
        }
        __syncthreads();
        if (in_g) {  // LN inputs are always K_==512 (single chunk)
            int r = tid >> 5, lane = tid & 31;
            float s = 0.f, q = 0.f;
            for (int k = lane; k < KCH; k += 32) { float v = xs[r * KCH + k]; s += v; q += v * v; }
            for (int off = 16; off; off >>= 1) { s += __shfl_down(s, off, 32); q += __shfl_down(q, off, 32); }
            if (lane == 0) { float m = s / KCH; sm[r] = m; sr[r] = rsqrtf(q / KCH - m * m + 1e-5f); }
            __syncthreads();
            for (int i = tid; i < BB * KCH; i += 256) {
                int r2 = i >> 9, k = i & (KCH - 1);
                xs[i] = (xs[i] - sm[r2]) * sr[r2] * in_g[k] + in_b[k];
            }
            __syncthreads();
        }
        const float* Wp = W + (size_t)(kc0 + ks * KPC) * N + col;
        int kbase = ks * KPC;
        #pragma unroll 4
        for (int k = 0; k < KPC; k += 4) {
            float w0 = Wp[(size_t)(k + 0) * N];
            float w1 = Wp[(size_t)(k + 1) * N];
            float w2 = Wp[(size_t)(k + 2) * N];
            float w3 = Wp[(size_t)(k + 3) * N];
            #pragma unroll
            for (int r = 0; r < BB; r++) {
                const float4 xv = *(const float4*)(xs + r * KCH + kbase + k);
                acc[r] += xv.x * w0 + xv.y * w1 + xv.z * w2 + xv.w * w3;
            }
        }
    }
    #pragma unroll
    for (int r = 0; r < BB; r++) part[(ks * BB + r) * CPB + c] = acc[r];
    __syncthreads();
    for (int o = tid; o < BB * CPB; o += 256) {
        int r = o / CPB, cc = o % CPB;
        int ocol = blockIdx.x * CPB + cc;
        float v = 0.f;
        #pragma unroll
        for (int s2 = 0; s2 < KSL; s2++) v += part[(s2 * BB + r) * CPB + cc];
        v += bias[ocol];
        if (relu) v = fmaxf(v, 0.f);
        if (res) v += rs[r * DD + ocol];
        out[(size_t)r * N + ocol] = v;
        if (kc) {
            if (ocol >= DD && ocol < 2 * DD)      kc[(size_t)r * (LLEN * DD) + (ocol - DD)] = v;
            else if (ocol >= 2 * DD)              vc[(size_t)r * (LLEN * DD) + (ocol - 2 * DD)] = v;
        }
    }
}

// -------------------------------------------------------- self-attention (t)
__global__ __launch_bounds__(64) void sattn_kernel(
    const float* __restrict__ qkv, const float* __restrict__ Ksa, const float* __restrict__ Vsa,
    float* __restrict__ attn_out, int l, int t)
{
    int b = blockIdx.x >> 3, h = blockIdx.x & 7;
    int lane = threadIdx.x;
    __shared__ float qsh[HDIM];
    __shared__ float ps[LLEN];
    qsh[lane] = qkv[b * (3 * DD) + h * HDIM + lane];
    __syncthreads();
    float s = -1e30f;
    if (lane <= t) {
        const float* kp = Ksa + (((size_t)l * BB + b) * LLEN + lane) * DD + h * HDIM;
        float d0 = 0.f;
        #pragma unroll 8
        for (int d = 0; d < HDIM; d++) d0 += qsh[d] * kp[d];
        s = d0 * 0.125f;
    }
    float mx = s;
    for (int off = 32; off; off >>= 1) mx = fmaxf(mx, __shfl_xor(mx, off));
    float p = (lane <= t) ? expf(s - mx) : 0.f;
    float sum = p;
    for (int off = 32; off; off >>= 1) sum += __shfl_xor(sum, off);
    if (lane < LLEN) ps[lane] = (lane <= t) ? p / sum : 0.f;
    __syncthreads();
    float o = 0.f;
    const float* vp = Vsa + (((size_t)l * BB + b) * LLEN) * DD + h * HDIM + lane;
    for (int j = 0; j <= t; j++) o += ps[j] * vp[(size_t)j * DD];
    attn_out[b * DD + h * HDIM + lane] = o;
}

// ------------------------------------------------------------ cross-attention
__global__ __launch_bounds__(128) void cattn_kernel(
    const float* __restrict__ qca, const float* __restrict__ Kmem, const float* __restrict__ Vmem,
    float* __restrict__ cattn_out, int l)
{
    int b = blockIdx.x >> 3, h = blockIdx.x & 7;
    int tid = threadIdx.x;
    __shared__ float qsh[HDIM];
    __shared__ float ps[SMEMN];
    __shared__ float red[4];
    __shared__ float po[2][HDIM];
    if (tid < HDIM) qsh[tid] = qca[b * DD + h * HDIM + tid];
    __syncthreads();
    const float* kp = Kmem + (((size_t)l * BB + b) * SMEMN + tid) * DD + h * HDIM;
    float s = 0.f;
    #pragma unroll 8
    for (int d = 0; d < HDIM; d++) s += qsh[d] * kp[d];
    s *= 0.125f;
    float mx = s;
    for (int off = 32; off; off >>= 1) mx = fmaxf(mx, __shfl_xor(mx, off));
    if ((tid & 63) == 0) red[tid >> 6] = mx;
    __syncthreads();
    mx = fmaxf(red[0], red[1]);
    float p = expf(s - mx);
    float sum = p;
    for (int off = 32; off; off >>= 1) sum += __shfl_xor(sum, off);
    if ((tid & 63) == 0) red[2 + (tid >> 6)] = sum;
    __syncthreads();
    sum = red[2] + red[3];
    ps[tid] = p / sum;
    __syncthreads();
    int d = tid & 63, half = tid >> 6;
    const float* vp = Vmem + (((size_t)l * BB + b) * SMEMN + half * 64) * DD + h * HDIM + d;
    float o = 0.f;
    for (int j = 0; j < 64; j++) o += ps[half * 64 + j] * vp[(size_t)j * DD];
    po[half][d] = o;
    __syncthreads();
    if (tid < HDIM) cattn_out[b * DD + h * HDIM + tid] = po[0][tid] + po[1][tid];
}

// ----------------------------------------------------- classifier + argmax(t)
__global__ __launch_bounds__(128) void clf_kernel(
    const float* __restrict__ y3, const float* __restrict__ g, const float* __restrict__ be,
    const float* __restrict__ Wc, const float* __restrict__ bc,
    float* __restrict__ out_logits, int* __restrict__ tokens, int t)
{
    int b = blockIdx.x, tid = threadIdx.x;
    __shared__ float xn[DD];
    __shared__ float red[4];
    __shared__ float rv[2];
    __shared__ int   ri[2];
    float s = 0.f, q = 0.f;
    for (int k = tid; k < DD; k += 128) { float v = y3[b * DD + k]; xn[k] = v; s += v; q += v * v; }
    for (int off = 32; off; off >>= 1) { s += __shfl_xor(s, off); q += __shfl_xor(q, off); }
    if ((tid & 63) == 0) { red[tid >> 6] = s; red[2 + (tid >> 6)] = q; }
    __syncthreads();
    s = red[0] + red[1]; q = red[2] + red[3];
    float m = s / DD, r = rsqrtf(q / DD - m * m + 1e-5f);
    for (int k = tid; k < DD; k += 128) xn[k] = (xn[k] - m) * r * g[k] + be[k];
    __syncthreads();
    float lg = bc[tid];
    #pragma unroll 8
    for (int k = 0; k < DD; k++) lg += xn[k] * Wc[(size_t)k * VV + tid];
    out_logits[((size_t)b * LLEN + t) * VV + tid] = lg;
    float bv = lg; int bi = tid;
    for (int off = 32; off; off >>= 1) {
        float ov = __shfl_xor(bv, off); int oi = __shfl_xor(bi, off);
        if (ov > bv || (ov == bv && oi < bi)) { bv = ov; bi = oi; }
    }
    if ((tid & 63) == 0) { rv[tid >> 6] = bv; ri[tid >> 6] = bi; }
    __syncthreads();
    if (tid == 0) {
        int best = (rv[1] > rv[0] || (rv[1] == rv[0] && ri[1] < ri[0])) ? ri[1] : ri[0];
        tokens[b * (LLEN + 1) + t + 1] = best;
    }
}

// ----------------------------------------------------------- finalize sampled
__global__ __launch_bounds__(64) void finalize_kernel(const int* __restrict__ tokens, float* __restrict__ outp) {
    int b = threadIdx.x;
    if (b < BB) {
        int eos = 0;
        for (int j = 1; j <= LLEN; j++) {
            if (tokens[b * (LLEN + 1) + j] == EOS_T) { eos = j; break; }
        }
        for (int j = 0; j <= LLEN; j++) {
            int v = tokens[b * (LLEN + 1) + j];
            if (eos != 0 && j > eos + 1) v = PAD_T;
            outp[b * (LLEN + 1) + j] = (float)v;
        }
    }
}

// --------------------------------------------------------------------- host
extern "C" void kernel_launch(void* const* d_in, const int* in_sizes, int n_in,
                              void* d_out, int out_size, void* d_ws, size_t ws_size,
                              hipStream_t stream) {
    const float* memory   = (const float*)d_in[0];
    const float* emb      = (const float*)d_in[1];
    const float* sa_qkv_w = (const float*)d_in[2];
    const float* sa_qkv_b = (const float*)d_in[3];
    const float* sa_out_w = (const float*)d_in[4];
    const float* sa_out_b = (const float*)d_in[5];
    const float* ca_q_w   = (const float*)d_in[6];
    const float* ca_q_b   = (const float*)d_in[7];
    const float* ca_kv_w  = (const float*)d_in[8];
    const float* ca_kv_b  = (const float*)d_in[9];
    const float* ca_out_w = (const float*)d_in[10];
    const float* ca_out_b = (const float*)d_in[11];
    const float* ln1_g    = (const float*)d_in[12];
    const float* ln1_b    = (const float*)d_in[13];
    const float* ln2_g    = (const float*)d_in[14];
    const float* ln2_b    = (const float*)d_in[15];
    const float* ln3_g    = (const float*)d_in[16];
    const float* ln3_b    = (const float*)d_in[17];
    const float* ffn_w1   = (const float*)d_in[18];
    const float* ffn_b1   = (const float*)d_in[19];
    const float* ffn_w2   = (const float*)d_in[20];
    const float* ffn_b2   = (const float*)d_in[21];
    const float* clf_w    = (const float*)d_in[22];
    const float* clf_b    = (const float*)d_in[23];

    float* ws = (float*)d_ws;
    int*   tokens = (int*)ws;                         // 264 ints (reserve 512 floats)
    float* Kmem = ws + 512;                           // [3][8][128][512]
    float* Vmem = Kmem + (size_t)3 * BB * SMEMN * DD; // [3][8][128][512]
    float* Ksa  = Vmem + (size_t)3 * BB * SMEMN * DD; // [3][8][32][512]
    float* Vsa  = Ksa  + (size_t)3 * BB * LLEN * DD;  // [3][8][32][512]
    float* x0   = Vsa  + (size_t)3 * BB * LLEN * DD;  // [8][512]
    float* qkvb = x0   + BB * DD;                     // [8][1536]
    float* attn = qkvb + BB * 3 * DD;                 // [8][512]
    float* y1   = attn + BB * DD;                     // [8][512]
    float* qca  = y1   + BB * DD;                     // [8][512]
    float* cat  = qca  + BB * DD;                     // [8][512]
    float* y2   = cat  + BB * DD;                     // [8][512]
    float* hb   = y2   + BB * DD;                     // [8][2048]
    float* y3   = hb   + BB * DFFN;                   // [8][512]

    float* out_logits  = (float*)d_out;
    float* out_sampled = out_logits + (size_t)BB * LLEN * VV;

    init_tokens_kernel<<<1, 512, 0, stream>>>(tokens);
    {
        dim3 g(16, 16, 3);
        memkv_kernel<<<g, 256, 0, stream>>>(memory, ca_kv_w, ca_kv_b, Kmem, Vmem);
    }

    for (int t = 0; t < LLEN; t++) {
        embed_kernel<<<BB, 256, 0, stream>>>(tokens, emb, x0, t);
        const float* xin = x0;
        const float* xg = nullptr;
        const float* xb = nullptr;
        for (int l = 0; l < NLAYER; l++) {
            const float* Wqkv = sa_qkv_w + (size_t)l * DD * 3 * DD;
            const float* bqkv = sa_qkv_b + (size_t)l * 3 * DD;
            float* kcp = Ksa + ((size_t)l * BB * LLEN + t) * DD;
            float* vcp = Vsa + ((size_t)l * BB * LLEN + t) * DD;
            gemv_ln_kernel<512><<<(3 * DD) / 64, 256, 0, stream>>>(
                xin, xg, xb, Wqkv, bqkv, 3 * DD,
                nullptr, nullptr, nullptr, qkvb, 0, kcp, vcp);

            sattn_kernel<<<BB * HH, 64, 0, stream>>>(qkvb, Ksa, Vsa, attn, l, t);

            gemv_ln_kernel<512><<<DD / 64, 256, 0, stream>>>(
                attn, nullptr, nullptr,
                sa_out_w + (size_t)l * DD * DD, sa_out_b + (size_t)l * DD, DD,
                xin, xg, xb, y1, 0, nullptr, nullptr);

            gemv_ln_kernel<512><<<DD / 64, 256, 0, stream>>>(
                y1, ln1_g + l * DD, ln1_b + l * DD,
                ca_q_w + (size_t)l * DD * DD, ca_q_b + (size_t)l * DD, DD,
                nullptr, nullptr, nullptr, qca, 0, nullptr, nullptr);

            cattn_kernel<<<BB * HH, 128, 0, stream>>>(qca, Kmem, Vmem, cat, l);

            gemv_ln_kernel<512><<<DD / 64, 256, 0, stream>>>(
                cat, nullptr, nullptr,
                ca_out_w + (size_t)l * DD * DD, ca_out_b + (size_t)l * DD, DD,
                y1, ln1_g + l * DD, ln1_b + l * DD, y2, 0, nullptr, nullptr);

            gemv_ln_kernel<512><<<DFFN / 64, 256, 0, stream>>>(
                y2, ln2_g + l * DD, ln2_b + l * DD,
                ffn_w1 + (size_t)l * DD * DFFN, ffn_b1 + (size_t)l * DFFN, DFFN,
                nullptr, nullptr, nullptr, hb, 1, nullptr, nullptr);

            gemv_ln_kernel<2048><<<DD / 64, 256, 0, stream>>>(
                hb, nullptr, nullptr,
                ffn_w2 + (size_t)l * DFFN * DD, ffn_b2 + (size_t)l * DD, DD,
                y2, ln2_g + l * DD, ln2_b + l * DD, y3, 0, nullptr, nullptr);

            xin = y3;
            xg = ln3_g + l * DD;
            xb = ln3_b + l * DD;
        }
        clf_kernel<<<BB, 128, 0, stream>>>(y3, ln3_g + 2 * DD, ln3_b + 2 * DD,
                                           clf_w, clf_b, out_logits, tokens, t);
    }
    finalize_kernel<<<1, 64, 0, stream>>>(tokens, out_sampled);
}

// Round 2
// 15518.326 us; speedup vs baseline: 1.1855x; 1.1855x over previous
//
#include <hip/hip_runtime.h>
#include <math.h>

#define BB 8
#define SMEMN 128
#define DD 512
#define HH 8
#define HDIM 64
#define DFFN 2048
#define NLAYER 3
#define VV 128
#define LLEN 32
#define SOS_T 1
#define EOS_T 2
#define PAD_T 0
#define NB 64

// ---------------------------------------------------------------- init tokens
__global__ __launch_bounds__(512) void init_tokens_kernel(int* __restrict__ tokens) {
    int i = threadIdx.x;
    if (i < BB * (LLEN + 1)) tokens[i] = (i % (LLEN + 1) == 0) ? SOS_T : PAD_T;
}

// ------------------------------------------------- memory @ ca_kv_w (hoisted)
__global__ __launch_bounds__(256) void memkv_kernel(
    const float* __restrict__ mem, const float* __restrict__ Wkv, const float* __restrict__ bkv,
    float* __restrict__ Kmem, float* __restrict__ Vmem)
{
    int l = blockIdx.z;
    const float* Wl = Wkv + (size_t)l * DD * (2 * DD);
    const float* bl = bkv + l * (2 * DD);
    int brow = blockIdx.y * 64, bcol = blockIdx.x * 64;
    __shared__ float As[64][20];
    __shared__ float Bs[16][68];
    int tid = threadIdx.x;
    int ty = tid / 16, tx = tid % 16;
    float acc[4][4] = {};
    for (int k0 = 0; k0 < DD; k0 += 16) {
        {
            int r = tid >> 2, kk = (tid & 3) * 4;
            const float4 av = *(const float4*)(mem + (size_t)(brow + r) * DD + k0 + kk);
            As[r][kk] = av.x; As[r][kk + 1] = av.y; As[r][kk + 2] = av.z; As[r][kk + 3] = av.w;
        }
        {
            int kb = tid >> 4, j = (tid & 15) * 4;
            const float4 bv = *(const float4*)(Wl + (size_t)(k0 + kb) * (2 * DD) + bcol + j);
            Bs[kb][j] = bv.x; Bs[kb][j + 1] = bv.y; Bs[kb][j + 2] = bv.z; Bs[kb][j + 3] = bv.w;
        }
        __syncthreads();
        #pragma unroll
        for (int kk2 = 0; kk2 < 16; kk2++) {
            float a0 = As[ty * 4 + 0][kk2], a1 = As[ty * 4 + 1][kk2];
            float a2 = As[ty * 4 + 2][kk2], a3 = As[ty * 4 + 3][kk2];
            float b0 = Bs[kk2][tx * 4 + 0], b1 = Bs[kk2][tx * 4 + 1];
            float b2 = Bs[kk2][tx * 4 + 2], b3 = Bs[kk2][tx * 4 + 3];
            acc[0][0] += a0 * b0; acc[0][1] += a0 * b1; acc[0][2] += a0 * b2; acc[0][3] += a0 * b3;
            acc[1][0] += a1 * b0; acc[1][1] += a1 * b1; acc[1][2] += a1 * b2; acc[1][3] += a1 * b3;
            acc[2][0] += a2 * b0; acc[2][1] += a2 * b1; acc[2][2] += a2 * b2; acc[2][3] += a2 * b3;
            acc[3][0] += a3 * b0; acc[3][1] += a3 * b1; acc[3][2] += a3 * b2; acc[3][3] += a3 * b3;
        }
        __syncthreads();
    }
    for (int i = 0; i < 4; i++)
        for (int j = 0; j < 4; j++) {
            int row = brow + ty * 4 + i, colg = bcol + tx * 4 + j;
            float v = acc[i][j] + bl[colg];
            if (colg < DD) Kmem[((size_t)l * (BB * SMEMN) + row) * DD + colg] = v;
            else           Vmem[((size_t)l * (BB * SMEMN) + row) * DD + (colg - DD)] = v;
        }
}

// ---------------------------------------------------------------- grid barrier
__device__ __forceinline__ void gbar(int* cnt, int target) {
    __syncthreads();
    if (threadIdx.x == 0) {
        __hip_atomic_fetch_add(cnt, 1, __ATOMIC_RELEASE, __HIP_MEMORY_SCOPE_AGENT);
        int spins = 0;
        while (__hip_atomic_load(cnt, __ATOMIC_RELAXED, __HIP_MEMORY_SCOPE_AGENT) < target) {
            __builtin_amdgcn_s_sleep(8);
            if (++spins > (1 << 22)) break;   // deadlock escape hatch; never trips normally
        }
        __threadfence();                      // agent acquire: invalidate L1/L2
    }
    __syncthreads();
}

// ---------------------------------------------------------------- LN in LDS
// xs: [8][512]; 256 threads = 8 rows x 32 lanes
__device__ __forceinline__ void ln_lds(float* xs, const float* __restrict__ g,
                                       const float* __restrict__ b, int tid,
                                       float* mS, float* rS) {
    int r = tid >> 5, lane = tid & 31;
    float s = 0.f, q = 0.f;
    for (int k = lane; k < DD; k += 32) { float v = xs[r * DD + k]; s += v; q += v * v; }
    for (int off = 16; off; off >>= 1) { s += __shfl_down(s, off, 32); q += __shfl_down(q, off, 32); }
    if (lane == 0) { float m = s / 512.f; mS[r] = m; rS[r] = rsqrtf(q / 512.f - m * m + 1e-5f); }
    __syncthreads();
    for (int i = tid; i < BB * DD; i += 256) {
        int r2 = i >> 9, k = i & 511;
        xs[i] = (xs[i] - mS[r2]) * rS[r2] * g[k] + b[k];
    }
}

// ---------------------------------------------------------------- GEMV core
// out[8][N] = xs[8][K] @ W[K][N] + bias (+relu) (+res[8][512]); block = 32 cols.
// Caller guarantees bid < N/32 and all 256 threads enter.
template <int K>
__device__ __forceinline__ void gemv_core(
    const float* __restrict__ xs, const float* __restrict__ W,
    const float* __restrict__ bias, int N,
    const float* __restrict__ res, float* __restrict__ out, int relu,
    float* __restrict__ kc, float* __restrict__ vc,
    float* part, int tid, int bid)
{
    const int c = tid & 31, ks = tid >> 5;
    const int col = (bid << 5) + c;
    const int KC = K >> 3;
    const int k0 = ks * KC;
    float acc[8] = {};
    const float* Wp = W + (size_t)k0 * N + col;
    for (int kk = 0; kk < KC; kk += 4) {
        float w0 = Wp[(size_t)(kk + 0) * N];
        float w1 = Wp[(size_t)(kk + 1) * N];
        float w2 = Wp[(size_t)(kk + 2) * N];
        float w3 = Wp[(size_t)(kk + 3) * N];
        #pragma unroll
        for (int r = 0; r < 8; ++r) {
            const float4 xv = *(const float4*)(xs + r * K + k0 + kk);
            acc[r] += xv.x * w0 + xv.y * w1 + xv.z * w2 + xv.w * w3;
        }
    }
    #pragma unroll
    for (int r = 0; r < 8; ++r) part[(ks * 8 + r) * 32 + c] = acc[r];
    __syncthreads();
    {
        int r = tid >> 5, cc = tid & 31;
        int ocol = (bid << 5) + cc;
        float v = 0.f;
        #pragma unroll
        for (int s = 0; s < 8; ++s) v += part[(s * 8 + r) * 32 + cc];
        v += bias[ocol];
        if (relu) v = fmaxf(v, 0.f);
        if (res) v += res[(r << 9) + ocol];
        out[(size_t)r * N + ocol] = v;
        if (kc) {
            if (ocol >= DD) {
                if (ocol < 2 * DD) kc[(size_t)r * (LLEN * DD) + (ocol - DD)] = v;
                else               vc[(size_t)r * (LLEN * DD) + (ocol - 2 * DD)] = v;
            }
        }
    }
}

// ---------------------------------------------------------------- megakernel
struct MegaParams {
    const float *emb;
    const float *sa_qkv_w, *sa_qkv_b, *sa_out_w, *sa_out_b;
    const float *ca_q_w, *ca_q_b, *ca_out_w, *ca_out_b;
    const float *ln1_g, *ln1_b, *ln2_g, *ln2_b, *ln3_g, *ln3_b;
    const float *ffn_w1, *ffn_b1, *ffn_w2, *ffn_b2, *clf_w, *clf_b;
    int* tokens; int* bar;
    float *Kmem, *Vmem, *Ksa, *Vsa;
    float *qkvb, *attn, *y1, *qca, *cat, *y2, *hb, *y3;
    float *xproc, *y1ln, *y2ln;
    float *out_logits, *out_sampled;
};

__global__ __launch_bounds__(256, 1) void mega_kernel(MegaParams p) {
    __shared__ float xs[BB * DFFN];      // 64 KB staging (max K = 2048)
    __shared__ float part[8 * 8 * 32];   // 8 KB gemv partials / scratch
    __shared__ float sred[512];          // attention scratch
    __shared__ float mS[8], rS[8];
    __shared__ float argv[2];
    __shared__ int   argi[2];
    const int tid = threadIdx.x, bid = blockIdx.x;
    int gen = 0;

    for (int t = 0; t < LLEN; ++t) {
        for (int l = 0; l < NLAYER; ++l) {
            // ---------------- qkv (+ embed / LN3 input prep) ----------------
            {
                const int nblk = (3 * DD) / 32;  // 48
                if (bid < nblk) {
                    if (l == 0) {
                        int pos = (t == 0) ? 0 : (t + 1);
                        for (int i = tid; i < BB * DD; i += 256) {
                            int r = i >> 9, d = i & 511;
                            int tok = p.tokens[r * (LLEN + 1) + t];
                            float freq = expf((float)(d & ~1) * (-9.210340371976184f / 512.0f));
                            float ang = (float)pos * freq;
                            float pev = (d & 1) ? cosf(ang) : sinf(ang);
                            xs[i] = p.emb[(size_t)tok * DD + d] * 22.62741699796952f + pev;
                        }
                        __syncthreads();
                    } else {
                        for (int i = tid; i < BB * DD; i += 256) xs[i] = p.y3[i];
                        __syncthreads();
                        ln_lds(xs, p.ln3_g + (l - 1) * DD, p.ln3_b + (l - 1) * DD, tid, mS, rS);
                        __syncthreads();
                    }
                    if (bid == 0)
                        for (int i = tid; i < BB * DD; i += 256) p.xproc[i] = xs[i];
                    gemv_core<512>(xs, p.sa_qkv_w + (size_t)l * DD * 3 * DD,
                                   p.sa_qkv_b + l * 3 * DD, 3 * DD,
                                   nullptr, p.qkvb, 0,
                                   p.Ksa + ((size_t)l * (BB * LLEN) + t) * DD,
                                   p.Vsa + ((size_t)l * (BB * LLEN) + t) * DD,
                                   part, tid, bid);
                }
                gbar(p.bar, (++gen) * NB);
            }
            // ---------------- self-attention ----------------
            {
                const int b = bid >> 3, h = bid & 7;
                if (tid < 64) sred[tid] = p.qkvb[b * (3 * DD) + h * HDIM + tid];
                __syncthreads();
                float* sc = part;
                const int w = tid >> 6, lane = tid & 63;
                const float* Kb = p.Ksa + ((size_t)(l * BB + b)) * (LLEN * DD) + h * HDIM;
                for (int j = w; j <= t; j += 4) {
                    float v = sred[lane] * Kb[(size_t)j * DD + lane];
                    for (int off = 32; off; off >>= 1) v += __shfl_down(v, off);
                    if (lane == 0) sc[j] = v * 0.125f;
                }
                __syncthreads();
                if (tid < 64) {
                    float s = (tid <= t) ? sc[tid] : -1e30f;
                    float mx = s;
                    for (int off = 32; off; off >>= 1) mx = fmaxf(mx, __shfl_xor(mx, off));
                    float pe2 = (tid <= t) ? expf(s - mx) : 0.f;
                    float sum = pe2;
                    for (int off = 32; off; off >>= 1) sum += __shfl_xor(sum, off);
                    if (tid <= t) sc[tid] = pe2 / sum;
                }
                __syncthreads();
                {
                    const float* Vb = p.Vsa + ((size_t)(l * BB + b)) * (LLEN * DD) + h * HDIM;
                    float o = 0.f;
                    for (int j = w; j <= t; j += 4) o += sc[j] * Vb[(size_t)j * DD + lane];
                    sred[64 + w * 64 + lane] = o;
                }
                __syncthreads();
                if (tid < 64)
                    p.attn[b * DD + h * HDIM + tid] =
                        sred[64 + tid] + sred[128 + tid] + sred[192 + tid] + sred[256 + tid];
                gbar(p.bar, (++gen) * NB);
            }
            // ---------------- self-attn out proj (+res x) ----------------
            {
                if (bid < 16) {
                    for (int i = tid; i < BB * DD; i += 256) xs[i] = p.attn[i];
                    __syncthreads();
                    gemv_core<512>(xs, p.sa_out_w + (size_t)l * DD * DD, p.sa_out_b + l * DD, DD,
                                   p.xproc, p.y1, 0, nullptr, nullptr, part, tid, bid);
                }
                gbar(p.bar, (++gen) * NB);
            }
            // ---------------- ca_q (LN1 input; stash LN1(y1)) ----------------
            {
                if (bid < 16) {
                    for (int i = tid; i < BB * DD; i += 256) xs[i] = p.y1[i];
                    __syncthreads();
                    ln_lds(xs, p.ln1_g + l * DD, p.ln1_b + l * DD, tid, mS, rS);
                    __syncthreads();
                    if (bid == 0)
                        for (int i = tid; i < BB * DD; i += 256) p.y1ln[i] = xs[i];
                    gemv_core<512>(xs, p.ca_q_w + (size_t)l * DD * DD, p.ca_q_b + l * DD, DD,
                                   nullptr, p.qca, 0, nullptr, nullptr, part, tid, bid);
                }
                gbar(p.bar, (++gen) * NB);
            }
            // ---------------- cross-attention ----------------
            {
                const int b = bid >> 3, h = bid & 7;
                if (tid < 64) sred[tid] = p.qca[b * DD + h * HDIM + tid];
                __syncthreads();
                float* sc = sred + 64;    // 128 scores
                float* po = sred + 192;   // 256 partials
                const int w = tid >> 6, lane = tid & 63;
                const float* Kb = p.Kmem + ((size_t)(l * BB + b)) * (SMEMN * DD) + h * HDIM;
                for (int j = w; j < SMEMN; j += 4) {
                    float v = sred[lane] * Kb[(size_t)j * DD + lane];
                    for (int off = 32; off; off >>= 1) v += __shfl_down(v, off);
                    if (lane == 0) sc[j] = v * 0.125f;
                }
                __syncthreads();
                if (tid < 64) {
                    float s0 = sc[tid], s1 = sc[tid + 64];
                    float mx = fmaxf(s0, s1);
                    for (int off = 32; off; off >>= 1) mx = fmaxf(mx, __shfl_xor(mx, off));
                    float e0 = expf(s0 - mx), e1 = expf(s1 - mx);
                    float sum = e0 + e1;
                    for (int off = 32; off; off >>= 1) sum += __shfl_xor(sum, off);
                    sc[tid] = e0 / sum; sc[tid + 64] = e1 / sum;
                }
                __syncthreads();
                {
                    const float* Vb = p.Vmem + ((size_t)(l * BB + b)) * (SMEMN * DD) + h * HDIM;
                    float o = 0.f;
                    for (int j = w; j < SMEMN; j += 4) o += sc[j] * Vb[(size_t)j * DD + lane];
                    po[w * 64 + lane] = o;
                }
                __syncthreads();
                if (tid < 64)
                    p.cat[b * DD + h * HDIM + tid] =
                        po[tid] + po[64 + tid] + po[128 + tid] + po[192 + tid];
                gbar(p.bar, (++gen) * NB);
            }
            // ---------------- cross-attn out proj (+res LN1(y1)) ----------------
            {
                if (bid < 16) {
                    for (int i = tid; i < BB * DD; i += 256) xs[i] = p.cat[i];
                    __syncthreads();
                    gemv_core<512>(xs, p.ca_out_w + (size_t)l * DD * DD, p.ca_out_b + l * DD, DD,
                                   p.y1ln, p.y2, 0, nullptr, nullptr, part, tid, bid);
                }
                gbar(p.bar, (++gen) * NB);
            }
            // ---------------- ffn1 (LN2 input; stash LN2(y2); relu) ----------------
            {
                // nblk = 2048/32 = 64 == NB, all blocks active
                for (int i = tid; i < BB * DD; i += 256) xs[i] = p.y2[i];
                __syncthreads();
                ln_lds(xs, p.ln2_g + l * DD, p.ln2_b + l * DD, tid, mS, rS);
                __syncthreads();
                if (bid == 0)
                    for (int i = tid; i < BB * DD; i += 256) p.y2ln[i] = xs[i];
                gemv_core<512>(xs, p.ffn_w1 + (size_t)l * DD * DFFN, p.ffn_b1 + l * DFFN, DFFN,
                               nullptr, p.hb, 1, nullptr, nullptr, part, tid, bid);
                gbar(p.bar, (++gen) * NB);
            }
            // ---------------- ffn2 (+res LN2(y2)) ----------------
            {
                if (bid < 16) {
                    for (int i = tid; i < BB * DFFN; i += 256) xs[i] = p.hb[i];
                    __syncthreads();
                    gemv_core<2048>(xs, p.ffn_w2 + (size_t)l * DFFN * DD, p.ffn_b2 + l * DD, DD,
                                    p.y2ln, p.y3, 0, nullptr, nullptr, part, tid, bid);
                }
                gbar(p.bar, (++gen) * NB);
            }
        }
        // ---------------- classifier + argmax ----------------
        {
            if (bid < 8) {
                for (int i = tid; i < DD; i += 256) xs[i] = p.y3[(bid << 9) + i];
                __syncthreads();
                float s = 0.f, q = 0.f;
                for (int k = tid; k < DD; k += 256) { float v = xs[k]; s += v; q += v * v; }
                for (int off = 32; off; off >>= 1) { s += __shfl_down(s, off); q += __shfl_down(q, off); }
                if ((tid & 63) == 0) { part[tid >> 6] = s; part[8 + (tid >> 6)] = q; }
                __syncthreads();
                s = part[0] + part[1] + part[2] + part[3];
                q = part[8] + part[9] + part[10] + part[11];
                float m = s / 512.f, ri = rsqrtf(q / 512.f - m * m + 1e-5f);
                const float* g3 = p.ln3_g + 2 * DD;
                const float* b3 = p.ln3_b + 2 * DD;
                for (int k = tid; k < DD; k += 256) xs[DD + k] = (xs[k] - m) * ri * g3[k] + b3[k];
                __syncthreads();
                {
                    int cl = tid & 127, kh = tid >> 7;  // K split in 2
                    float lg = 0.f;
                    const float* Wc = p.clf_w + (size_t)kh * 256 * VV + cl;
                    const float* xh = xs + DD + kh * 256;
                    for (int k = 0; k < 256; ++k) lg += xh[k] * Wc[(size_t)k * VV];
                    part[tid] = lg;
                }
                __syncthreads();
                if (tid < 128) {
                    float lg = part[tid] + part[128 + tid] + p.clf_b[tid];
                    p.out_logits[((size_t)bid * LLEN + t) * VV + tid] = lg;
                    float bv = lg; int bi = tid;
                    for (int off = 32; off; off >>= 1) {
                        float ov = __shfl_xor(bv, off); int oi = __shfl_xor(bi, off);
                        if (ov > bv || (ov == bv && oi < bi)) { bv = ov; bi = oi; }
                    }
                    if ((tid & 63) == 0) { argv[tid >> 6] = bv; argi[tid >> 6] = bi; }
                }
                __syncthreads();
                if (tid == 0) {
                    int best = (argv[1] > argv[0] || (argv[1] == argv[0] && argi[1] < argi[0]))
                                   ? argi[1] : argi[0];
                    p.tokens[bid * (LLEN + 1) + t + 1] = best;
                }
            }
            gbar(p.bar, (++gen) * NB);
        }
    }
    // ---------------- finalize sampled ----------------
    if (bid == 0 && tid < BB) {
        int b = tid;
        int eos = 0;
        for (int j = 1; j <= LLEN; j++) {
            if (p.tokens[b * (LLEN + 1) + j] == EOS_T) { eos = j; break; }
        }
        for (int j = 0; j <= LLEN; j++) {
            int v = p.tokens[b * (LLEN + 1) + j];
            if (eos != 0 && j > eos + 1) v = PAD_T;
            p.out_sampled[b * (LLEN + 1) + j] = (float)v;
        }
    }
}

// --------------------------------------------------------------------- host
extern "C" void kernel_launch(void* const* d_in, const int* in_sizes, int n_in,
                              void* d_out, int out_size, void* d_ws, size_t ws_size,
                              hipStream_t stream) {
    const float* memory   = (const float*)d_in[0];
    const float* emb      = (const float*)d_in[1];
    const float* sa_qkv_w = (const float*)d_in[2];
    const float* sa_qkv_b = (const float*)d_in[3];
    const float* sa_out_w = (const float*)d_in[4];
    const float* sa_out_b = (const float*)d_in[5];
    const float* ca_q_w   = (const float*)d_in[6];
    const float* ca_q_b   = (const float*)d_in[7];
    const float* ca_kv_w  = (const float*)d_in[8];
    const float* ca_kv_b  = (const float*)d_in[9];
    const float* ca_out_w = (const float*)d_in[10];
    const float* ca_out_b = (const float*)d_in[11];
    const float* ln1_g    = (const float*)d_in[12];
    const float* ln1_b    = (const float*)d_in[13];
    const float* ln2_g    = (const float*)d_in[14];
    const float* ln2_b    = (const float*)d_in[15];
    const float* ln3_g    = (const float*)d_in[16];
    const float* ln3_b    = (const float*)d_in[17];
    const float* ffn_w1   = (const float*)d_in[18];
    const float* ffn_b1   = (const float*)d_in[19];
    const float* ffn_w2   = (const float*)d_in[20];
    const float* ffn_b2   = (const float*)d_in[21];
    const float* clf_w    = (const float*)d_in[22];
    const float* clf_b    = (const float*)d_in[23];

    float* f = (float*)d_ws;
    int*   bar    = (int*)d_ws;          // f[0..63]
    int*   tokens = (int*)d_ws + 64;     // 264 ints
    float* Kmem = f + 512;
    float* Vmem = Kmem + (size_t)NLAYER * BB * SMEMN * DD;
    float* Ksa  = Vmem + (size_t)NLAYER * BB * SMEMN * DD;
    float* Vsa  = Ksa  + (size_t)NLAYER * BB * LLEN * DD;
    float* qkvb = Vsa  + (size_t)NLAYER * BB * LLEN * DD;
    float* attn = qkvb + BB * 3 * DD;
    float* y1   = attn + BB * DD;
    float* qca  = y1   + BB * DD;
    float* cat  = qca  + BB * DD;
    float* y2   = cat  + BB * DD;
    float* hb   = y2   + BB * DD;
    float* y3   = hb   + BB * DFFN;
    float* xproc= y3   + BB * DD;
    float* y1ln = xproc+ BB * DD;
    float* y2ln = y1ln + BB * DD;

    float* out_logits  = (float*)d_out;
    float* out_sampled = out_logits + (size_t)BB * LLEN * VV;

    hipMemsetAsync(d_ws, 0, 4096, stream);  // reset barrier counter (+ tokens region)
    init_tokens_kernel<<<1, 512, 0, stream>>>(tokens);
    {
        dim3 g(16, 16, 3);
        memkv_kernel<<<g, 256, 0, stream>>>(memory, ca_kv_w, ca_kv_b, Kmem, Vmem);
    }

    MegaParams p;
    p.emb = emb;
    p.sa_qkv_w = sa_qkv_w; p.sa_qkv_b = sa_qkv_b;
    p.sa_out_w = sa_out_w; p.sa_out_b = sa_out_b;
    p.ca_q_w = ca_q_w; p.ca_q_b = ca_q_b;
    p.ca_out_w = ca_out_w; p.ca_out_b = ca_out_b;
    p.ln1_g = ln1_g; p.ln1_b = ln1_b;
    p.ln2_g = ln2_g; p.ln2_b = ln2_b;
    p.ln3_g = ln3_g; p.ln3_b = ln3_b;
    p.ffn_w1 = ffn_w1; p.ffn_b1 = ffn_b1;
    p.ffn_w2 = ffn_w2; p.ffn_b2 = ffn_b2;
    p.clf_w = clf_w; p.clf_b = clf_b;
    p.tokens = tokens; p.bar = bar;
    p.Kmem = Kmem; p.Vmem = Vmem; p.Ksa = Ksa; p.Vsa = Vsa;
    p.qkvb = qkvb; p.attn = attn; p.y1 = y1; p.qca = qca;
    p.cat = cat; p.y2 = y2; p.hb = hb; p.y3 = y3;
    p.xproc = xproc; p.y1ln = y1ln; p.y2ln = y2ln;
    p.out_logits = out_logits; p.out_sampled = out_sampled;

    mega_kernel<<<NB, 256, 0, stream>>>(p);
}